// Round 2
// baseline (423.571 us; speedup 1.0000x reference)
//
#include <hip/hip_runtime.h>

namespace {

constexpr int kB  = 8;
constexpr int kCF = 32;
constexpr int kCP = 4;
constexpr int kS  = 64;
constexpr int kL  = 32;
constexpr int kPlane = kS * kS;                         // 4096
constexpr long long kChStride = (long long)kS * kPlane; // 262144 floats per channel
constexpr int kMCos = kL * kPlane;                      // 131072 cos positions / sample
constexpr int kCosBlocksPerB = kMCos / (256 * 4);       // 128
constexpr int kKlElems = kCP * kL * kPlane;             // 524288 kl elements / sample
constexpr int kKlBlocksPerB = kKlElems / (256 * 4);     // 512
constexpr int kGridCos = kB * kCosBlocksPerB;           // 1024
constexpr int kGridKl  = kB * kKlBlocksPerB;            // 4096
constexpr int kGridTotal = kGridCos + kGridKl;          // 5120
constexpr float kClampEps = 1e-6f;
constexpr float kCosEps = 1e-8f;

__device__ __forceinline__ float block_reduce_sum(float v) {
  #pragma unroll
  for (int off = 32; off > 0; off >>= 1) v += __shfl_down(v, off, 64);
  __shared__ float smem[4];
  const int lane = threadIdx.x & 63;
  const int wid  = threadIdx.x >> 6;
  if (lane == 0) smem[wid] = v;
  __syncthreads();
  float r = 0.f;
  if (threadIdx.x == 0) r = smem[0] + smem[1] + smem[2] + smem[3];
  __syncthreads();  // smem reuse safety for repeated calls
  return r;
}

__device__ __forceinline__ float kl_term(float sv, float tv) {
  const float sc = fminf(fmaxf(sv, kClampEps), 1.f - kClampEps);
  const float tc = fminf(fmaxf(tv, kClampEps), 1.f - kClampEps);
  return tc * (__logf(tc) - __logf(sc));
}

// Single fused kernel. Blocks [0, kGridCos): cosine partials over sf/tf
// slices. Blocks [kGridCos, kGridTotal): KL partials over sp/tp slices.
// Last block to finish (device-scope ticket) folds all partials -> out[0].
// Deterministic: every block writes its own partial slot; the fold reads
// slots in fixed array order, so the result is replay-stable.
__global__ __launch_bounds__(256) void fused_kernel(
    const float* __restrict__ sf, const float* __restrict__ tf,
    const float* __restrict__ sp, const float* __restrict__ tp,
    const int* __restrict__ cur_start, const int* __restrict__ adj_start,
    float* __restrict__ partial, unsigned int* __restrict__ counter,
    float* __restrict__ out) {
  const int blk = blockIdx.x;
  float local = 0.f;

  if (blk < kGridCos) {
    const int b     = blk >> 7;                 // / kCosBlocksPerB
    const int chunk = blk & (kCosBlocksPerB - 1);
    const int cs = cur_start[b];
    const int as = adj_start[b];
    const int pos = chunk * 1024 + (int)threadIdx.x * 4;  // in [0, 131072)
    const int dd  = pos >> 12;
    const int rem = pos & (kPlane - 1);
    const float* sptr = sf + ((long long)b * kCF * kS + (cs + dd)) * kPlane + rem;
    const float* tptr = tf + ((long long)b * kCF * kS + (as + dd)) * kPlane + rem;

    float4 dot = make_float4(0.f, 0.f, 0.f, 0.f);
    float4 na  = make_float4(0.f, 0.f, 0.f, 0.f);
    float4 nb  = make_float4(0.f, 0.f, 0.f, 0.f);
    #pragma unroll 8
    for (int c = 0; c < kCF; ++c) {
      const float4 a = *reinterpret_cast<const float4*>(sptr + c * kChStride);
      const float4 t = *reinterpret_cast<const float4*>(tptr + c * kChStride);
      dot.x += a.x * t.x; dot.y += a.y * t.y; dot.z += a.z * t.z; dot.w += a.w * t.w;
      na.x  += a.x * a.x; na.y  += a.y * a.y; na.z  += a.z * a.z; na.w  += a.w * a.w;
      nb.x  += t.x * t.x; nb.y  += t.y * t.y; nb.z  += t.z * t.z; nb.w  += t.w * t.w;
    }
    local =
        dot.x / (fmaxf(sqrtf(na.x), kCosEps) * fmaxf(sqrtf(nb.x), kCosEps)) +
        dot.y / (fmaxf(sqrtf(na.y), kCosEps) * fmaxf(sqrtf(nb.y), kCosEps)) +
        dot.z / (fmaxf(sqrtf(na.z), kCosEps) * fmaxf(sqrtf(nb.z), kCosEps)) +
        dot.w / (fmaxf(sqrtf(na.w), kCosEps) * fmaxf(sqrtf(nb.w), kCosEps));
  } else {
    const int kblk  = blk - kGridCos;
    const int b     = kblk >> 9;                // / kKlBlocksPerB
    const int chunk = kblk & (kKlBlocksPerB - 1);
    const int cs = cur_start[b];
    const int as = adj_start[b];
    const int pos = chunk * 1024 + (int)threadIdx.x * 4;  // in [0, 524288)
    const int c   = pos >> 17;
    const int m   = pos & (kMCos - 1);
    const int dd  = m >> 12;
    const int rem = m & (kPlane - 1);
    const float4 s4 = *reinterpret_cast<const float4*>(
        sp + ((long long)(b * kCP + c) * kS + (cs + dd)) * kPlane + rem);
    const float4 t4 = *reinterpret_cast<const float4*>(
        tp + ((long long)(b * kCP + c) * kS + (as + dd)) * kPlane + rem);
    local = kl_term(s4.x, t4.x) + kl_term(s4.y, t4.y) +
            kl_term(s4.z, t4.z) + kl_term(s4.w, t4.w);
  }

  const float s = block_reduce_sum(local);
  __shared__ bool amLast;
  if (threadIdx.x == 0) {
    partial[blk] = s;
    __threadfence();  // release: make partial visible device-wide
    const unsigned int t = __hip_atomic_fetch_add(
        counter, 1u, __ATOMIC_ACQ_REL, __HIP_MEMORY_SCOPE_AGENT);
    amLast = (t == (unsigned int)(kGridTotal - 1));
  }
  __syncthreads();
  if (!amLast) return;

  // Final fold (one block). Agent-scope loads bypass stale caches.
  float cosAcc = 0.f, klAcc = 0.f;
  for (int i = threadIdx.x; i < kGridCos; i += 256)
    cosAcc += __hip_atomic_load(&partial[i], __ATOMIC_RELAXED, __HIP_MEMORY_SCOPE_AGENT);
  for (int i = kGridCos + (int)threadIdx.x; i < kGridTotal; i += 256)
    klAcc  += __hip_atomic_load(&partial[i], __ATOMIC_RELAXED, __HIP_MEMORY_SCOPE_AGENT);
  const float cosTot = block_reduce_sum(cosAcc);
  const float klTot  = block_reduce_sum(klAcc);
  if (threadIdx.x == 0) {
    out[0] = 1.f - cosTot / (float)(kB * kMCos) + 0.3f * klTot / (float)kB;
  }
}

}  // namespace

extern "C" void kernel_launch(void* const* d_in, const int* in_sizes, int n_in,
                              void* d_out, int out_size, void* d_ws, size_t ws_size,
                              hipStream_t stream) {
  const float* sf = (const float*)d_in[0];
  const float* tf = (const float*)d_in[1];
  const float* sp = (const float*)d_in[2];
  const float* tp = (const float*)d_in[3];
  const int* cur_start = (const int*)d_in[4];
  const int* adj_start = (const int*)d_in[5];
  float* out = (float*)d_out;
  float* partial = (float*)d_ws;                       // kGridTotal floats
  unsigned int* counter =
      (unsigned int*)((char*)d_ws + kGridTotal * sizeof(float));  // +20480 B

  // Reset the ticket counter every call (d_ws is poisoned once, never
  // re-poisoned between graph replays). 4-byte async memset is capturable.
  hipMemsetAsync(counter, 0, sizeof(unsigned int), stream);

  fused_kernel<<<kGridTotal, 256, 0, stream>>>(
      sf, tf, sp, tp, cur_start, adj_start, partial, counter, out);
}

// Round 3
// 58.666 us; speedup vs baseline: 7.2200x; 7.2200x over previous
//
#include <hip/hip_runtime.h>

namespace {

constexpr int kB  = 8;
constexpr int kCF = 32;
constexpr int kCP = 4;
constexpr int kS  = 64;
constexpr int kL  = 32;
constexpr int kPlane = kS * kS;                         // 4096
constexpr long long kChStride = (long long)kS * kPlane; // 262144 floats per channel
constexpr int kMCos = kL * kPlane;                      // 131072 cos positions / sample
constexpr int kCosBlocksPerB = kMCos / (256 * 4);       // 128
constexpr int kKlElems = kCP * kL * kPlane;             // 524288 kl elements / sample
constexpr int kKlBlocksPerB = kKlElems / (256 * 8);     // 256 (2048 floats/block)
constexpr int kGridCos = kB * kCosBlocksPerB;           // 1024
constexpr int kGridKl  = kB * kKlBlocksPerB;            // 2048
constexpr int kGridTotal = kGridCos + kGridKl;          // 3072
constexpr float kClampEps = 1e-6f;
constexpr float kCosEps = 1e-8f;

__device__ __forceinline__ float block_reduce_sum(float v) {
  #pragma unroll
  for (int off = 32; off > 0; off >>= 1) v += __shfl_down(v, off, 64);
  __shared__ float smem[4];
  const int lane = threadIdx.x & 63;
  const int wid  = threadIdx.x >> 6;
  if (lane == 0) smem[wid] = v;
  __syncthreads();
  float r = 0.f;
  if (threadIdx.x == 0) r = smem[0] + smem[1] + smem[2] + smem[3];
  __syncthreads();  // smem reuse safety for repeated calls
  return r;
}

__device__ __forceinline__ float kl_term(float sv, float tv) {
  const float sc = fminf(fmaxf(sv, kClampEps), 1.f - kClampEps);
  const float tc = fminf(fmaxf(tv, kClampEps), 1.f - kClampEps);
  return tc * (__logf(tc) - __logf(sc));
}

// Fused main kernel: blocks [0, kGridCos) = cosine partials (long-running,
// scheduled first so they all start at t=0); blocks [kGridCos, kGridTotal)
// = KL partials (short, backfill behind cos). No fences/atomics — the
// kernel-boundary release + next dispatch's acquire handle visibility.
__global__ __launch_bounds__(256) void fused_main(
    const float* __restrict__ sf, const float* __restrict__ tf,
    const float* __restrict__ sp, const float* __restrict__ tp,
    const int* __restrict__ cur_start, const int* __restrict__ adj_start,
    float* __restrict__ partial) {
  const int blk = blockIdx.x;
  float local = 0.f;

  if (blk < kGridCos) {
    const int b     = blk >> 7;                 // / kCosBlocksPerB
    const int chunk = blk & (kCosBlocksPerB - 1);
    const int cs = cur_start[b];
    const int as = adj_start[b];
    const int pos = chunk * 1024 + (int)threadIdx.x * 4;  // in [0, 131072)
    const int dd  = pos >> 12;
    const int rem = pos & (kPlane - 1);
    const float* sptr = sf + ((long long)b * kCF * kS + (cs + dd)) * kPlane + rem;
    const float* tptr = tf + ((long long)b * kCF * kS + (as + dd)) * kPlane + rem;

    float4 dot = make_float4(0.f, 0.f, 0.f, 0.f);
    float4 na  = make_float4(0.f, 0.f, 0.f, 0.f);
    float4 nb  = make_float4(0.f, 0.f, 0.f, 0.f);
    #pragma unroll 8
    for (int c = 0; c < kCF; ++c) {
      const float4 a = *reinterpret_cast<const float4*>(sptr + c * kChStride);
      const float4 t = *reinterpret_cast<const float4*>(tptr + c * kChStride);
      dot.x += a.x * t.x; dot.y += a.y * t.y; dot.z += a.z * t.z; dot.w += a.w * t.w;
      na.x  += a.x * a.x; na.y  += a.y * a.y; na.z  += a.z * a.z; na.w  += a.w * a.w;
      nb.x  += t.x * t.x; nb.y  += t.y * t.y; nb.z  += t.z * t.z; nb.w  += t.w * t.w;
    }
    local =
        dot.x / (fmaxf(sqrtf(na.x), kCosEps) * fmaxf(sqrtf(nb.x), kCosEps)) +
        dot.y / (fmaxf(sqrtf(na.y), kCosEps) * fmaxf(sqrtf(nb.y), kCosEps)) +
        dot.z / (fmaxf(sqrtf(na.z), kCosEps) * fmaxf(sqrtf(nb.z), kCosEps)) +
        dot.w / (fmaxf(sqrtf(na.w), kCosEps) * fmaxf(sqrtf(nb.w), kCosEps));
  } else {
    const int kblk  = blk - kGridCos;
    const int b     = kblk >> 8;                // / kKlBlocksPerB
    const int chunk = kblk & (kKlBlocksPerB - 1);
    const int cs = cur_start[b];
    const int as = adj_start[b];
    const int base = chunk * 2048;              // 2048 floats per block
    #pragma unroll
    for (int half = 0; half < 2; ++half) {
      const int pos = base + half * 1024 + (int)threadIdx.x * 4;  // in [0, 524288)
      const int c   = pos >> 17;
      const int m   = pos & (kMCos - 1);
      const int dd  = m >> 12;
      const int rem = m & (kPlane - 1);
      const float4 s4 = *reinterpret_cast<const float4*>(
          sp + ((long long)(b * kCP + c) * kS + (cs + dd)) * kPlane + rem);
      const float4 t4 = *reinterpret_cast<const float4*>(
          tp + ((long long)(b * kCP + c) * kS + (as + dd)) * kPlane + rem);
      local += kl_term(s4.x, t4.x) + kl_term(s4.y, t4.y) +
               kl_term(s4.z, t4.z) + kl_term(s4.w, t4.w);
    }
  }

  const float s = block_reduce_sum(local);
  if (threadIdx.x == 0) partial[blk] = s;
}

// Single block: fold all partials into the scalar loss.
__global__ __launch_bounds__(256) void final_kernel(
    const float* __restrict__ partial, float* __restrict__ out) {
  float cosAcc = 0.f, klAcc = 0.f;
  for (int i = threadIdx.x; i < kGridCos; i += 256) cosAcc += partial[i];
  for (int i = kGridCos + (int)threadIdx.x; i < kGridTotal; i += 256)
    klAcc += partial[i];
  const float cosTot = block_reduce_sum(cosAcc);
  const float klTot  = block_reduce_sum(klAcc);
  if (threadIdx.x == 0) {
    // mean_b [ (1 - cos_sum_b/131072) + 0.3*kl_b ]
    out[0] = 1.f - cosTot / (float)(kB * kMCos) + 0.3f * klTot / (float)kB;
  }
}

}  // namespace

extern "C" void kernel_launch(void* const* d_in, const int* in_sizes, int n_in,
                              void* d_out, int out_size, void* d_ws, size_t ws_size,
                              hipStream_t stream) {
  const float* sf = (const float*)d_in[0];
  const float* tf = (const float*)d_in[1];
  const float* sp = (const float*)d_in[2];
  const float* tp = (const float*)d_in[3];
  const int* cur_start = (const int*)d_in[4];
  const int* adj_start = (const int*)d_in[5];
  float* out = (float*)d_out;
  float* partial = (float*)d_ws;  // kGridTotal * 4 = 12288 bytes

  fused_main<<<kGridTotal, 256, 0, stream>>>(
      sf, tf, sp, tp, cur_start, adj_start, partial);
  final_kernel<<<1, 256, 0, stream>>>(partial, out);
}

// Round 5
// 56.531 us; speedup vs baseline: 7.4927x; 1.0378x over previous
//
#include <hip/hip_runtime.h>

namespace {

constexpr int kB  = 8;
constexpr int kCF = 32;
constexpr int kCP = 4;
constexpr int kS  = 64;
constexpr int kL  = 32;
constexpr int kPlane = kS * kS;                         // 4096
constexpr long long kChStride = (long long)kS * kPlane; // 262144 floats per channel
constexpr int kMCos = kL * kPlane;                      // 131072 cos positions / sample
constexpr int kCosBlocksPerB = kMCos / (256 * 4);       // 128
constexpr int kKlElems = kCP * kL * kPlane;             // 524288 kl elements / sample
constexpr int kKlBlocksPerB = kKlElems / (256 * 8);     // 256 (2048 floats/block)
constexpr int kGridCos = kB * kCosBlocksPerB;           // 1024
constexpr int kGridKl  = kB * kKlBlocksPerB;            // 2048
constexpr int kGridTotal = kGridCos + kGridKl;          // 3072
constexpr float kClampEps = 1e-6f;
constexpr float kCosEps = 1e-8f;

// Native clang vector type: __builtin_nontemporal_load requires a pointer to
// scalar or native vector (HIP_vector_type<float,4> is a struct -> rejected).
typedef float floatx4 __attribute__((ext_vector_type(4)));

__device__ __forceinline__ floatx4 nt_load4(const float* p) {
  return __builtin_nontemporal_load(reinterpret_cast<const floatx4*>(p));
}

__device__ __forceinline__ float block_reduce_sum(float v) {
  #pragma unroll
  for (int off = 32; off > 0; off >>= 1) v += __shfl_down(v, off, 64);
  __shared__ float smem[4];
  const int lane = threadIdx.x & 63;
  const int wid  = threadIdx.x >> 6;
  if (lane == 0) smem[wid] = v;
  __syncthreads();
  float r = 0.f;
  if (threadIdx.x == 0) r = smem[0] + smem[1] + smem[2] + smem[3];
  __syncthreads();  // smem reuse safety for repeated calls
  return r;
}

__device__ __forceinline__ float kl_term(float sv, float tv) {
  const float sc = fminf(fmaxf(sv, kClampEps), 1.f - kClampEps);
  const float tc = fminf(fmaxf(tv, kClampEps), 1.f - kClampEps);
  return tc * (__logf(tc) - __logf(sc));
}

// Fused main kernel: blocks [0, kGridCos) = cosine partials (heavy, 256 KB
// each, scheduled first); blocks [kGridCos, kGridTotal) = KL partials
// (light, backfill). All big-tensor loads are nontemporal: single-touch
// stream, no reuse -> skip LLC allocation.
__global__ __launch_bounds__(256) void fused_main(
    const float* __restrict__ sf, const float* __restrict__ tf,
    const float* __restrict__ sp, const float* __restrict__ tp,
    const int* __restrict__ cur_start, const int* __restrict__ adj_start,
    float* __restrict__ partial) {
  const int blk = blockIdx.x;
  float local = 0.f;

  if (blk < kGridCos) {
    const int b     = blk >> 7;                 // / kCosBlocksPerB
    const int chunk = blk & (kCosBlocksPerB - 1);
    const int cs = cur_start[b];
    const int as = adj_start[b];
    const int pos = chunk * 1024 + (int)threadIdx.x * 4;  // in [0, 131072)
    const int dd  = pos >> 12;
    const int rem = pos & (kPlane - 1);
    const float* sptr = sf + ((long long)b * kCF * kS + (cs + dd)) * kPlane + rem;
    const float* tptr = tf + ((long long)b * kCF * kS + (as + dd)) * kPlane + rem;

    floatx4 dot = {0.f, 0.f, 0.f, 0.f};
    floatx4 na  = {0.f, 0.f, 0.f, 0.f};
    floatx4 nb  = {0.f, 0.f, 0.f, 0.f};
    #pragma unroll 8
    for (int c = 0; c < kCF; ++c) {
      const floatx4 a = nt_load4(sptr + c * kChStride);
      const floatx4 t = nt_load4(tptr + c * kChStride);
      dot += a * t;
      na  += a * a;
      nb  += t * t;
    }
    local =
        dot.x / (fmaxf(sqrtf(na.x), kCosEps) * fmaxf(sqrtf(nb.x), kCosEps)) +
        dot.y / (fmaxf(sqrtf(na.y), kCosEps) * fmaxf(sqrtf(nb.y), kCosEps)) +
        dot.z / (fmaxf(sqrtf(na.z), kCosEps) * fmaxf(sqrtf(nb.z), kCosEps)) +
        dot.w / (fmaxf(sqrtf(na.w), kCosEps) * fmaxf(sqrtf(nb.w), kCosEps));
  } else {
    const int kblk  = blk - kGridCos;
    const int b     = kblk >> 8;                // / kKlBlocksPerB
    const int chunk = kblk & (kKlBlocksPerB - 1);
    const int cs = cur_start[b];
    const int as = adj_start[b];
    const int base = chunk * 2048;              // 2048 floats per block
    #pragma unroll
    for (int half = 0; half < 2; ++half) {
      const int pos = base + half * 1024 + (int)threadIdx.x * 4;  // in [0, 524288)
      const int c   = pos >> 17;
      const int m   = pos & (kMCos - 1);
      const int dd  = m >> 12;
      const int rem = m & (kPlane - 1);
      const floatx4 s4 = nt_load4(
          sp + ((long long)(b * kCP + c) * kS + (cs + dd)) * kPlane + rem);
      const floatx4 t4 = nt_load4(
          tp + ((long long)(b * kCP + c) * kS + (as + dd)) * kPlane + rem);
      local += kl_term(s4.x, t4.x) + kl_term(s4.y, t4.y) +
               kl_term(s4.z, t4.z) + kl_term(s4.w, t4.w);
    }
  }

  const float s = block_reduce_sum(local);
  if (threadIdx.x == 0) partial[blk] = s;
}

// Single block: fold all partials into the scalar loss.
__global__ __launch_bounds__(256) void final_kernel(
    const float* __restrict__ partial, float* __restrict__ out) {
  float cosAcc = 0.f, klAcc = 0.f;
  for (int i = threadIdx.x; i < kGridCos; i += 256) cosAcc += partial[i];
  for (int i = kGridCos + (int)threadIdx.x; i < kGridTotal; i += 256)
    klAcc += partial[i];
  const float cosTot = block_reduce_sum(cosAcc);
  const float klTot  = block_reduce_sum(klAcc);
  if (threadIdx.x == 0) {
    // mean_b [ (1 - cos_sum_b/131072) + 0.3*kl_b ]
    out[0] = 1.f - cosTot / (float)(kB * kMCos) + 0.3f * klTot / (float)kB;
  }
}

}  // namespace

extern "C" void kernel_launch(void* const* d_in, const int* in_sizes, int n_in,
                              void* d_out, int out_size, void* d_ws, size_t ws_size,
                              hipStream_t stream) {
  const float* sf = (const float*)d_in[0];
  const float* tf = (const float*)d_in[1];
  const float* sp = (const float*)d_in[2];
  const float* tp = (const float*)d_in[3];
  const int* cur_start = (const int*)d_in[4];
  const int* adj_start = (const int*)d_in[5];
  float* out = (float*)d_out;
  float* partial = (float*)d_ws;  // kGridTotal * 4 = 12288 bytes

  fused_main<<<kGridTotal, 256, 0, stream>>>(
      sf, tf, sp, tp, cur_start, adj_start, partial);
  final_kernel<<<1, 256, 0, stream>>>(partial, out);
}

// Round 6
// 53.420 us; speedup vs baseline: 7.9291x; 1.0582x over previous
//
#include <hip/hip_runtime.h>

namespace {

constexpr int kB  = 8;
constexpr int kCF = 32;
constexpr int kCP = 4;
constexpr int kS  = 64;
constexpr int kL  = 32;
constexpr int kPlane = kS * kS;                         // 4096
constexpr long long kChStride = (long long)kS * kPlane; // 262144 floats per channel
constexpr int kMCos = kL * kPlane;                      // 131072 cos positions / sample
constexpr int kKlElems = kCP * kL * kPlane;             // 524288 kl floats / sample
constexpr int kGrid = 2048;                             // 256 blocks per sample; = exact co-residency (8 blk/CU)
constexpr int kBlocksPerB = kGrid / kB;                 // 256
constexpr float kClampEps = 1e-6f;
constexpr float kCosEps = 1e-8f;
constexpr float kCosScale = 1.0f / (float)((long long)kB * kMCos);
constexpr float kKlScale  = 0.3f / (float)kB;

// Native clang vector types (__builtin_nontemporal_load rejects the
// HIP_vector_type structs).
typedef float floatx2 __attribute__((ext_vector_type(2)));
typedef float floatx4 __attribute__((ext_vector_type(4)));

__device__ __forceinline__ floatx2 nt_load2(const float* p) {
  return __builtin_nontemporal_load(reinterpret_cast<const floatx2*>(p));
}
__device__ __forceinline__ floatx4 nt_load4(const float* p) {
  return __builtin_nontemporal_load(reinterpret_cast<const floatx4*>(p));
}

__device__ __forceinline__ float block_reduce_sum(float v) {
  #pragma unroll
  for (int off = 32; off > 0; off >>= 1) v += __shfl_down(v, off, 64);
  __shared__ float smem[4];
  const int lane = threadIdx.x & 63;
  const int wid  = threadIdx.x >> 6;
  if (lane == 0) smem[wid] = v;
  __syncthreads();
  float r = 0.f;
  if (threadIdx.x == 0) r = smem[0] + smem[1] + smem[2] + smem[3];
  __syncthreads();
  return r;
}

__device__ __forceinline__ float kl_term(float sv, float tv) {
  const float sc = fminf(fmaxf(sv, kClampEps), 1.f - kClampEps);
  const float tc = fminf(fmaxf(tv, kClampEps), 1.f - kClampEps);
  return tc * (__logf(tc) - __logf(sc));
}

// Uniform fused kernel: 2048 identical blocks (exactly the co-residency
// capacity at 4 waves/block), each handling 512 cosine positions (float2
// NT loads over 32 channels of sf/tf) + 2048 KL floats (float4 NT loads
// of sp/tp). Identical per-block duration -> single dispatch round, no
// straggler tail. partial[blk] = pre-scaled contribution; loss = 1 + sum.
__global__ __launch_bounds__(256) void fused_main(
    const float* __restrict__ sf, const float* __restrict__ tf,
    const float* __restrict__ sp, const float* __restrict__ tp,
    const int* __restrict__ cur_start, const int* __restrict__ adj_start,
    float* __restrict__ partial) {
  const int blk = blockIdx.x;
  const int b   = blk >> 8;                // sample (256 blocks per sample)
  const int i   = blk & (kBlocksPerB - 1);
  const int cs  = cur_start[b];
  const int as  = adj_start[b];

  // ---- cosine part: positions [i*512, i*512+512) of sample b ----
  float cosLocal;
  {
    const int posbase = i << 9;                        // i*512, plane-aligned run
    const int dd  = posbase >> 12;                     // constant per block
    const int rem = (posbase & (kPlane - 1)) + (int)threadIdx.x * 2;
    const float* s0 = sf + ((long long)b * kCF * kS + (cs + dd)) * kPlane + rem;
    const float* t0 = tf + ((long long)b * kCF * kS + (as + dd)) * kPlane + rem;
    floatx2 dot = {0.f, 0.f};
    floatx2 na  = {0.f, 0.f};
    floatx2 nb  = {0.f, 0.f};
    #pragma unroll 8
    for (int c = 0; c < kCF; ++c) {
      const floatx2 a = nt_load2(s0 + c * kChStride);
      const floatx2 t = nt_load2(t0 + c * kChStride);
      dot += a * t;
      na  += a * a;
      nb  += t * t;
    }
    cosLocal =
        dot.x / (fmaxf(sqrtf(na.x), kCosEps) * fmaxf(sqrtf(nb.x), kCosEps)) +
        dot.y / (fmaxf(sqrtf(na.y), kCosEps) * fmaxf(sqrtf(nb.y), kCosEps));
  }

  // ---- KL part: floats [i*2048, i*2048+2048) of sample b's slice ----
  float klLocal = 0.f;
  {
    const int fbase = i << 11;                         // i*2048
    const int c   = fbase >> 17;                       // prob channel 0..3
    const int m   = fbase & (kMCos - 1);
    const int ddk = m >> 12;                           // constant per block
    const int remk = m & (kPlane - 1);                 // 0 or 2048
    const float* sb = sp + ((long long)(b * kCP + c) * kS + (cs + ddk)) * kPlane + remk;
    const float* tb = tp + ((long long)(b * kCP + c) * kS + (as + ddk)) * kPlane + remk;
    #pragma unroll
    for (int h = 0; h < 2; ++h) {
      const int off = h * 1024 + (int)threadIdx.x * 4;
      const floatx4 s4 = nt_load4(sb + off);
      const floatx4 t4 = nt_load4(tb + off);
      klLocal += kl_term(s4.x, t4.x) + kl_term(s4.y, t4.y) +
                 kl_term(s4.z, t4.z) + kl_term(s4.w, t4.w);
    }
  }

  const float local = -cosLocal * kCosScale + klLocal * kKlScale;
  const float s = block_reduce_sum(local);
  if (threadIdx.x == 0) partial[blk] = s;
}

// Single block: loss = 1 + sum(partial[0..kGrid)).
__global__ __launch_bounds__(256) void final_kernel(
    const float* __restrict__ partial, float* __restrict__ out) {
  float acc = 0.f;
  for (int i = threadIdx.x; i < kGrid; i += 256) acc += partial[i];
  const float tot = block_reduce_sum(acc);
  if (threadIdx.x == 0) out[0] = 1.f + tot;
}

}  // namespace

extern "C" void kernel_launch(void* const* d_in, const int* in_sizes, int n_in,
                              void* d_out, int out_size, void* d_ws, size_t ws_size,
                              hipStream_t stream) {
  const float* sf = (const float*)d_in[0];
  const float* tf = (const float*)d_in[1];
  const float* sp = (const float*)d_in[2];
  const float* tp = (const float*)d_in[3];
  const int* cur_start = (const int*)d_in[4];
  const int* adj_start = (const int*)d_in[5];
  float* out = (float*)d_out;
  float* partial = (float*)d_ws;  // kGrid * 4 = 8192 bytes

  fused_main<<<kGrid, 256, 0, stream>>>(
      sf, tf, sp, tp, cur_start, adj_start, partial);
  final_kernel<<<1, 256, 0, stream>>>(partial, out);
}